// Round 9
// baseline (218.712 us; speedup 1.0000x reference)
//
#include <hip/hip_runtime.h>
#include <hip/hip_bf16.h>

// Problem constants
constexpr int cB = 4;
constexpr int cN = 4096;
constexpr int cD = 512;
constexpr int cK = 64;
constexpr int cNB = cB * cN;       // 16384 rows
constexpr int cNP = cN + 1;        // 4097 prefix rows
constexpr int cCS = 16;            // chunk size for scans
constexpr int cNC = cN / cCS;      // 256 chunks per batch
constexpr int cNC1 = cNC + 1;      // 257

typedef unsigned short u16;
typedef unsigned int u32;
typedef unsigned long long u64;
typedef __bf16 bf16x8 __attribute__((ext_vector_type(8)));
typedef float f32x4 __attribute__((ext_vector_type(4)));

// ---- workspace layout (in floats) ----
constexpr size_t OFF_H    = 0;                                  // cNB*cK
constexpr size_t OFF_T1   = OFF_H    + (size_t)cNB * cK;        // cNB
constexpr size_t OFF_T2   = OFF_T1   + cNB;                     // cNB
constexpr size_t OFF_T2S  = OFF_T2   + cNB;                     // cNB (sorted)
constexpr size_t OFF_IDX  = OFF_T2S  + cNB;                     // cNB (int)
constexpr size_t OFF_EPL  = OFF_IDX  + cNB;                     // cB*cNP*cK
constexpr size_t OFF_GNL  = OFF_EPL  + (size_t)cB * cNP * cK;   // cB*cNP*cK
constexpr size_t OFF_EPS  = OFF_GNL  + (size_t)cB * cNP * cK;   // cB*cNP
constexpr size_t OFF_GNS  = OFF_EPS  + (size_t)cB * cNP;        // cB*cNP
constexpr size_t OFF_CHE  = OFF_GNS  + (size_t)cB * cNP;        // cB*cNC*cK
constexpr size_t OFF_CHG  = OFF_CHE  + (size_t)cB * cNC * cK;
constexpr size_t OFF_CHES = OFF_CHG  + (size_t)cB * cNC * cK;   // cB*cNC
constexpr size_t OFF_CHGS = OFF_CHES + (size_t)cB * cNC;
constexpr size_t OFF_OFE  = OFF_CHGS + (size_t)cB * cNC;        // cB*cNC1*cK
constexpr size_t OFF_OFG  = OFF_OFE  + (size_t)cB * cNC1 * cK;
constexpr size_t OFF_OFES = OFF_OFG  + (size_t)cB * cNC1 * cK;  // cB*cNC1
constexpr size_t OFF_OFGS = OFF_OFES + (size_t)cB * cNC1;
constexpr size_t OFF_XB16 = OFF_OFGS + (size_t)cB * cNC1;       // cNB*cD u16 = /2 floats
constexpr size_t OFF_WB16 = OFF_XB16 + (size_t)cNB * cD / 2;    // cK*cD u16
constexpr size_t OFF_P    = OFF_WB16 + (size_t)cK * cD / 2;     // cNB int
constexpr size_t OFF_CNT  = OFF_P + cNB;                        // 1 u32

__device__ __forceinline__ u16 f2bf(float f) {
    unsigned u = __float_as_uint(f);
    u += 0x7fffu + ((u >> 16) & 1u);   // RNE
    return (u16)(u >> 16);
}
__device__ __forceinline__ u32 pk2(float a, float b) {
    return (u32)f2bf(a) | ((u32)f2bf(b) << 16);
}
// monotone float -> sortable uint (ascending)
__device__ __forceinline__ u32 f2sort(float f) {
    u32 b = __float_as_uint(f);
    u32 mask = (u32)((int)b >> 31);
    return b ^ (mask | 0x80000000u);
}
// software grid barrier: monotonic counter, release fence on arrive,
// acquire load on spin. Safe iff all blocks co-resident (512 blocks,
// launch_bounds(256,2) => 2 blocks/CU guaranteed).
__device__ __forceinline__ void gbar(u32* cnt, u32 target) {
    __syncthreads();
    if (threadIdx.x == 0) {
        __threadfence();
        atomicAdd(cnt, 1u);
        while (__hip_atomic_load(cnt, __ATOMIC_ACQUIRE, __HIP_MEMORY_SCOPE_AGENT) < target) {
            __builtin_amdgcn_s_sleep(2);
        }
    }
    __syncthreads();
}

// ---------------------------------------------------------------------------
// k_prep (544 blocks): blocks <512: one pass over x -> xb16 (bf16) + exact
// f32 t1/t2 via in-block fold of Wa with Wb/Wc. Blocks >=512: Wa -> wab16.
// Block 512 also zero-inits the back-end barrier counter.
// ---------------------------------------------------------------------------
__global__ __launch_bounds__(256) void k_prep(
    const float* __restrict__ x, const float* __restrict__ Wa,
    const float* __restrict__ Wb, const float* __restrict__ wbb,
    const float* __restrict__ Wc, const float* __restrict__ wcb,
    u16* __restrict__ xb16, u16* __restrict__ wab16,
    float* __restrict__ t1, float* __restrict__ t2, u32* __restrict__ cnt)
{
    __shared__ float wabL[cD], wacL[cD];
    int t = threadIdx.x;
    if (blockIdx.x >= 512) {           // wprep slice: 32 blocks x 256 x 4 elems
        if (blockIdx.x == 512 && t == 0) cnt[0] = 0;
        int i4 = (((int)blockIdx.x - 512) * 256 + t) * 4;
        float4 v = *(const float4*)(Wa + i4);
        uint2 p = {pk2(v.x, v.y), pk2(v.z, v.w)};
        *(uint2*)(wab16 + i4) = p;
        return;
    }
    float s1a = 0.f, s2a = 0.f, s1b = 0.f, s2b = 0.f;
#pragma unroll 8
    for (int k = 0; k < cK; ++k) {
        float wbk = Wb[k], wck = Wc[k];
        float wa1 = Wa[k * cD + t];
        float wa2 = Wa[k * cD + t + 256];
        s1a += wa1 * wbk; s2a += wa1 * wck;
        s1b += wa2 * wbk; s2b += wa2 * wck;
    }
    wabL[t] = s1a; wacL[t] = s2a; wabL[t + 256] = s1b; wacL[t + 256] = s2b;
    __syncthreads();

    int w = t >> 6, lane = t & 63;
    int d1 = lane * 4, d2 = 256 + lane * 4;
    float4 wbA = *(const float4*)&wabL[d1], wbB = *(const float4*)&wabL[d2];
    float4 wcA = *(const float4*)&wacL[d1], wcB = *(const float4*)&wacL[d2];
    float wbbv = wbb[0], wcbv = wcb[0];
#pragma unroll 2
    for (int rr = 0; rr < 8; ++rr) {
        int row = blockIdx.x * 32 + w * 8 + rr;
        const float* xp = x + (size_t)row * cD;
        float4 a  = *(const float4*)(xp + d1);
        float4 bq = *(const float4*)(xp + d2);
        uint2 pa = {pk2(a.x, a.y), pk2(a.z, a.w)};
        uint2 pb = {pk2(bq.x, bq.y), pk2(bq.z, bq.w)};
        *(uint2*)(xb16 + (size_t)row * cD + d1) = pa;
        *(uint2*)(xb16 + (size_t)row * cD + d2) = pb;
        float p1 = a.x*wbA.x + a.y*wbA.y + a.z*wbA.z + a.w*wbA.w
                 + bq.x*wbB.x + bq.y*wbB.y + bq.z*wbB.z + bq.w*wbB.w;
        float p2 = a.x*wcA.x + a.y*wcA.y + a.z*wcA.z + a.w*wcA.w
                 + bq.x*wcB.x + bq.y*wcB.y + bq.z*wcB.z + bq.w*wcB.w;
#pragma unroll
        for (int off = 32; off > 0; off >>= 1) {
            p1 += __shfl_down(p1, off, 64);
            p2 += __shfl_down(p2, off, 64);
        }
        if (lane == 0) { t1[row] = p1 + wbbv; t2[row] = p2 + wcbv; }
    }
}

// ---------------------------------------------------------------------------
// k_projrank (768 blocks): <256 bf16-MFMA GEMM tiles; 256..511 brute-force
// rank (u64 keys in LDS); 512..767 p-search: p_i = #{j : t2_j < -T1_i}
// (float keys in LDS) == lower_bound(t2s, -T1_i). Slices co-schedule per CU.
// ---------------------------------------------------------------------------
__global__ __launch_bounds__(256) void k_projrank(
    const u16* __restrict__ xb16, const u16* __restrict__ wab16,
    const float* __restrict__ t2, const float* __restrict__ t1,
    float* __restrict__ h, float* __restrict__ t2s, int* __restrict__ idxs,
    int* __restrict__ pidx)
{
    __shared__ u64 shbuf[4096 + 128];   // 33.75 KB max (rank slice)
    int t = threadIdx.x;
    if (blockIdx.x < 256) {
        u16* xs = (u16*)shbuf;
        u16* was = xs + 64 * 32;
        int rowbase = blockIdx.x * 64;
        int w = t >> 6, lane = t & 63, m = lane & 15, quad = lane >> 4;
        int grow = w * 16 + (lane >> 2);
        int gcol = (lane & 3) * 8;
        const u16* xg = xb16 + (size_t)(rowbase + grow) * cD + gcol;
        const u16* wg = wab16 + (size_t)grow * cD + gcol;
        int lidx = grow * 32 + gcol;

        f32x4 acc[4] = {{0.f,0.f,0.f,0.f},{0.f,0.f,0.f,0.f},
                        {0.f,0.f,0.f,0.f},{0.f,0.f,0.f,0.f}};
        uint4 xv = *(const uint4*)(xg);
        uint4 wv = *(const uint4*)(wg);
        for (int s = 0; s < 16; ++s) {
            __syncthreads();
            *(uint4*)&xs[lidx] = xv;
            *(uint4*)&was[lidx] = wv;
            if (s < 15) {
                xv = *(const uint4*)(xg + (s + 1) * 32);
                wv = *(const uint4*)(wg + (s + 1) * 32);
            }
            __syncthreads();
            bf16x8 av = *(const bf16x8*)&xs[(w * 16 + m) * 32 + quad * 8];
#pragma unroll
            for (int g = 0; g < 4; ++g) {
                bf16x8 bv = *(const bf16x8*)&was[(g * 16 + m) * 32 + quad * 8];
                acc[g] = __builtin_amdgcn_mfma_f32_16x16x32_bf16(av, bv, acc[g], 0, 0, 0);
            }
        }
#pragma unroll
        for (int g = 0; g < 4; ++g) {
#pragma unroll
            for (int r4 = 0; r4 < 4; ++r4) {
                int row = w * 16 + quad * 4 + r4;
                h[(size_t)(rowbase + row) * cK + g * 16 + m] = acc[g][r4];
            }
        }
    } else if (blockIdx.x < 512) {
        u64* keys = shbuf;
        int* part = (int*)(shbuf + 4096);
        int rb = blockIdx.x - 256;
        int b = rb >> 6;
        int rowgrp = rb & 63;
        for (int i = t; i < cN; i += 256)
            keys[i] = ((u64)f2sort(t2[b * cN + i]) << 32) | (u32)i;
        __syncthreads();
        int lane = t & 63, subset = t >> 6;
        u64 mykey = keys[rowgrp * 64 + lane];
        int s0 = subset * 1024;
        int cnt = 0;
#pragma unroll 8
        for (int kk = 0; kk < 1024; ++kk)
            cnt += (keys[s0 + kk] < mykey) ? 1 : 0;
        part[subset * 64 + lane] = cnt;
        __syncthreads();
        if (t < 64) {
            int jj = rowgrp * 64 + t;
            int rank = part[t] + part[64 + t] + part[128 + t] + part[192 + t];
            t2s[b * cN + rank] = t2[b * cN + jj];
            idxs[b * cN + rank] = jj;
        }
    } else {
        float* keysf = (float*)shbuf;                 // 16 KB
        int* part = (int*)(shbuf + 2048);
        int rb = blockIdx.x - 512;
        int b = rb >> 6;
        int rowgrp = rb & 63;
        for (int i = t; i < cN; i += 256)
            keysf[i] = t2[b * cN + i];
        __syncthreads();
        int lane = t & 63, subset = t >> 6;
        float key = -t1[b * cN + rowgrp * 64 + lane];
        int s0 = subset * 1024;
        int cnt = 0;
#pragma unroll 8
        for (int kk = 0; kk < 1024; ++kk)
            cnt += (keysf[s0 + kk] < key) ? 1 : 0;
        part[subset * 64 + lane] = cnt;
        __syncthreads();
        if (t < 64) {
            pidx[b * cN + rowgrp * 64 + t] =
                part[t] + part[64 + t] + part[128 + t] + part[192 + t];
        }
    }
}

// ---------------------------------------------------------------------------
// k_backend (512 blocks x 256, launch_bounds(256,2) => all co-resident):
//  phase 1: 2048 wave-tasks = (batch, chunk-of-16, {E,G}) local scans
//  phase 2: 8 blocks do the two-level chunk-offset scans
//  phase 3: 8 rows/block output combine (p precomputed)
// separated by software grid barriers on cnt (monotonic targets 512, 1024).
// ---------------------------------------------------------------------------
__global__ __launch_bounds__(256, 2) void k_backend(
    const float* __restrict__ t1, const float* __restrict__ t2s,
    const int* __restrict__ idxs, const float* __restrict__ h,
    const int* __restrict__ pidx,
    float* __restrict__ EpL, float* __restrict__ GnL,
    float* __restrict__ eps_l, float* __restrict__ gns_l,
    float* __restrict__ chE, float* __restrict__ chG,
    float* __restrict__ chEs, float* __restrict__ chGs,
    float* __restrict__ ofE, float* __restrict__ ofG,
    float* __restrict__ ofEs, float* __restrict__ ofGs,
    const float* __restrict__ bias, float* __restrict__ out,
    u32* __restrict__ cnt)
{
    __shared__ float wsum[4][64];
    int t = threadIdx.x;
    int lane = t & 63, w = t >> 6;

    // ---- phase 1: chunk scans (one (b,c,dir) per wave) ----
    {
        int gw = blockIdx.x * 4 + w;       // 0..2047
        int dir = gw >> 10;                // 0 = E, 1 = G
        int b = (gw >> 8) & 3;
        int c = gw & 255;
        int base = b * cN + c * cCS;
        size_t rowbase = ((size_t)b * cNP + c * cCS) * cK;
        int sbase = b * cNP + c * cCS;
        float M2 = t2s[b * cN + cN - 1];
        int   idxv = (lane < cCS) ? idxs[base + lane] : 0;
        float t2v  = (lane < cCS) ? t2s[base + lane] : 0.f;
        float hv[cCS];
#pragma unroll
        for (int i = 0; i < cCS; ++i) {
            int j = __shfl(idxv, i, 64);
            hv[i] = h[((size_t)b * cN + j) * cK + lane];
        }
        if (dir == 0) {
            float ee[cCS];
#pragma unroll
            for (int i = 0; i < cCS; ++i)
                ee[i] = __expf(__shfl(t2v, i, 64) - M2);
            if (c == cNC - 1) {
                EpL[((size_t)b * cNP + cN) * cK + lane] = 0.f;
                if (lane == 0) eps_l[b * cNP + cN] = 0.f;
            }
            float acc = 0.f, accs = 0.f;
#pragma unroll
            for (int i = cCS - 1; i >= 0; --i) {
                acc += ee[i] * hv[i]; accs += ee[i];
                EpL[rowbase + (size_t)i * cK + lane] = acc;
                if (lane == 0) eps_l[sbase + i] = accs;
            }
            chE[((size_t)b * cNC + c) * cK + lane] = acc;
            if (lane == 0) chEs[b * cNC + c] = accs;
        } else {
            float gg[cCS];
#pragma unroll
            for (int i = 0; i < cCS; ++i)
                gg[i] = __expf(0.2f * (__shfl(t2v, i, 64) - M2));
            if (c == cNC - 1) {
                GnL[((size_t)b * cNP + cN) * cK + lane] = 0.f;
                if (lane == 0) gns_l[b * cNP + cN] = 0.f;
            }
            float acc = 0.f, accs = 0.f;
#pragma unroll
            for (int i = 0; i < cCS; ++i) {
                GnL[rowbase + (size_t)i * cK + lane] = acc;
                if (lane == 0) gns_l[sbase + i] = accs;
                acc += gg[i] * hv[i]; accs += gg[i];
            }
            chG[((size_t)b * cNC + c) * cK + lane] = acc;
            if (lane == 0) chGs[b * cNC + c] = accs;
        }
    }
    gbar(cnt, 512);

    // ---- phase 2: chunk-offset scans (blocks 0..7) ----
    if (blockIdx.x < 8) {
        int dir = blockIdx.x & 1;          // 0 = E(suffix), 1 = G(prefix)
        int b = blockIdx.x >> 1;
        const float* ch = dir ? chG : chE;
        float* of = dir ? ofG : ofE;
        int c0 = w * 64;
        float cv[64];
        float s = 0.f;
#pragma unroll
        for (int i = 0; i < 64; ++i) {
            cv[i] = ch[((size_t)b * cNC + c0 + i) * cK + lane];
            s += cv[i];
        }
        wsum[w][lane] = s;
        __syncthreads();
        float base = 0.f;
        if (dir == 0) { for (int w2 = w + 1; w2 < 4; ++w2) base += wsum[w2][lane]; }
        else          { for (int w2 = 0; w2 < w; ++w2) base += wsum[w2][lane]; }
        if (dir == 0) {
            float run = base;
#pragma unroll
            for (int i = 63; i >= 0; --i) {
                of[((size_t)b * cNC1 + c0 + i) * cK + lane] = run;
                run += cv[i];
            }
            if (w == 0) of[((size_t)b * cNC1 + cNC) * cK + lane] = 0.f;
        } else {
            float run = base;
#pragma unroll
            for (int i = 0; i < 64; ++i) {
                of[((size_t)b * cNC1 + c0 + i) * cK + lane] = run;
                run += cv[i];
            }
            if (w == 3) of[((size_t)b * cNC1 + cNC) * cK + lane] = run;
        }
        if (w == 0) {
            const float* chs = dir ? chGs : chEs;
            float* ofs = dir ? ofGs : ofEs;
            float e0 = chs[b * cNC + lane * 4 + 0];
            float e1 = chs[b * cNC + lane * 4 + 1];
            float e2 = chs[b * cNC + lane * 4 + 2];
            float e3 = chs[b * cNC + lane * 4 + 3];
            float p = e0 + e1 + e2 + e3;
            if (dir == 0) {
                float s2 = p;
#pragma unroll
                for (int off = 1; off < 64; off <<= 1) {
                    float tv = __shfl_down(s2, off, 64);
                    if (lane + off < 64) s2 += tv;
                }
                float excl = s2 - p;
                ofs[b * cNC1 + lane * 4 + 0] = excl + e1 + e2 + e3;
                ofs[b * cNC1 + lane * 4 + 1] = excl + e2 + e3;
                ofs[b * cNC1 + lane * 4 + 2] = excl + e3;
                ofs[b * cNC1 + lane * 4 + 3] = excl;
                if (lane == 0) ofs[b * cNC1 + cNC] = 0.f;
            } else {
                float s2 = p;
#pragma unroll
                for (int off = 1; off < 64; off <<= 1) {
                    float tv = __shfl_up(s2, off, 64);
                    if (lane >= off) s2 += tv;
                }
                float excl = s2 - p;
                ofs[b * cNC1 + lane * 4 + 0] = excl;
                ofs[b * cNC1 + lane * 4 + 1] = excl + e0;
                ofs[b * cNC1 + lane * 4 + 2] = excl + e0 + e1;
                ofs[b * cNC1 + lane * 4 + 3] = excl + e0 + e1 + e2;
                if (lane == 63) ofs[b * cNC1 + cNC] = s2;
            }
        }
    }
    gbar(cnt, 1024);

    // ---- phase 3: output combine, 8 rows/block ----
#pragma unroll 2
    for (int g = 0; g < 8; ++g) {
        int r = g * 2048 + blockIdx.x * 4 + w;
        int b = r >> 12;
        float T1 = t1[r];
        float M2 = t2s[b * cN + cN - 1];
        float smax = T1 + M2;
        float m = fmaxf(smax, 0.2f * smax);
        float A  = __expf(smax - m);
        float Cc = __expf(0.2f * smax - m);
        int p = pidx[r];
        int c = p >> 4;
        size_t pr = ((size_t)b * cNP + p) * cK + lane;
        size_t cr = ((size_t)b * cNC1 + c) * cK + lane;
        float num = A * (EpL[pr] + ofE[cr]) + Cc * (GnL[pr] + ofG[cr]);
        float den = A * (eps_l[(size_t)b * cNP + p] + ofEs[b * cNC1 + c])
                  + Cc * (gns_l[(size_t)b * cNP + p] + ofGs[b * cNC1 + c]);
        out[(size_t)r * cK + lane] = num / den + bias[lane];
    }
}

// ---------------------------------------------------------------------------
extern "C" void kernel_launch(void* const* d_in, const int* in_sizes, int n_in,
                              void* d_out, int out_size, void* d_ws, size_t ws_size,
                              hipStream_t stream)
{
    const float* x    = (const float*)d_in[0];
    const float* Wa   = (const float*)d_in[1];
    const float* Wb   = (const float*)d_in[2];
    const float* wbb  = (const float*)d_in[3];
    const float* Wc   = (const float*)d_in[4];
    const float* wcb  = (const float*)d_in[5];
    const float* bias = (const float*)d_in[6];
    float* out = (float*)d_out;

    float* ws = (float*)d_ws;
    float* h     = ws + OFF_H;
    float* t1    = ws + OFF_T1;
    float* t2    = ws + OFF_T2;
    float* t2s   = ws + OFF_T2S;
    int*   idxs  = (int*)(ws + OFF_IDX);
    float* EpL   = ws + OFF_EPL;
    float* GnL   = ws + OFF_GNL;
    float* eps_l = ws + OFF_EPS;
    float* gns_l = ws + OFF_GNS;
    float* chE   = ws + OFF_CHE;
    float* chG   = ws + OFF_CHG;
    float* chEs  = ws + OFF_CHES;
    float* chGs  = ws + OFF_CHGS;
    float* ofE   = ws + OFF_OFE;
    float* ofG   = ws + OFF_OFG;
    float* ofEs  = ws + OFF_OFES;
    float* ofGs  = ws + OFF_OFGS;
    u16*   xb16  = (u16*)(ws + OFF_XB16);
    u16*   wab16 = (u16*)(ws + OFF_WB16);
    int*   pidx  = (int*)(ws + OFF_P);
    u32*   cnt   = (u32*)(ws + OFF_CNT);

    k_prep<<<544, 256, 0, stream>>>(x, Wa, Wb, wbb, Wc, wcb, xb16, wab16, t1, t2, cnt);
    k_projrank<<<768, 256, 0, stream>>>(xb16, wab16, t2, t1, h, t2s, idxs, pidx);
    k_backend<<<512, 256, 0, stream>>>(t1, t2s, idxs, h, pidx,
                                       EpL, GnL, eps_l, gns_l,
                                       chE, chG, chEs, chGs,
                                       ofE, ofG, ofEs, ofGs,
                                       bias, out, cnt);
}

// Round 10
// 202.741 us; speedup vs baseline: 1.0788x; 1.0788x over previous
//
#include <hip/hip_runtime.h>
#include <hip/hip_bf16.h>

// Problem constants
constexpr int cB = 4;
constexpr int cN = 4096;
constexpr int cD = 512;
constexpr int cK = 64;
constexpr int cNB = cB * cN;       // 16384 rows
constexpr int cNP = cN + 1;        // 4097 prefix rows
constexpr int cCS = 16;            // chunk size for scans
constexpr int cNC = cN / cCS;      // 256 chunks per batch
constexpr int cNC1 = cNC + 1;      // 257

typedef unsigned short u16;
typedef unsigned int u32;
typedef unsigned long long u64;
typedef __bf16 bf16x8 __attribute__((ext_vector_type(8)));
typedef float f32x4 __attribute__((ext_vector_type(4)));

// ---- workspace layout (in floats) ----
constexpr size_t OFF_H    = 0;                                  // cNB*cK
constexpr size_t OFF_T1   = OFF_H    + (size_t)cNB * cK;        // cNB
constexpr size_t OFF_T2   = OFF_T1   + cNB;                     // cNB
constexpr size_t OFF_T2S  = OFF_T2   + cNB;                     // cNB (sorted)
constexpr size_t OFF_IDX  = OFF_T2S  + cNB;                     // cNB (int)
constexpr size_t OFF_EPL  = OFF_IDX  + cNB;                     // cB*cNP*cK
constexpr size_t OFF_GNL  = OFF_EPL  + (size_t)cB * cNP * cK;   // cB*cNP*cK
constexpr size_t OFF_EPS  = OFF_GNL  + (size_t)cB * cNP * cK;   // cB*cNP
constexpr size_t OFF_GNS  = OFF_EPS  + (size_t)cB * cNP;        // cB*cNP
constexpr size_t OFF_CHE  = OFF_GNS  + (size_t)cB * cNP;        // cB*cNC*cK
constexpr size_t OFF_CHG  = OFF_CHE  + (size_t)cB * cNC * cK;
constexpr size_t OFF_CHES = OFF_CHG  + (size_t)cB * cNC * cK;   // cB*cNC
constexpr size_t OFF_CHGS = OFF_CHES + (size_t)cB * cNC;
constexpr size_t OFF_OFE  = OFF_CHGS + (size_t)cB * cNC;        // cB*cNC1*cK
constexpr size_t OFF_OFG  = OFF_OFE  + (size_t)cB * cNC1 * cK;
constexpr size_t OFF_OFES = OFF_OFG  + (size_t)cB * cNC1 * cK;  // cB*cNC1
constexpr size_t OFF_OFGS = OFF_OFES + (size_t)cB * cNC1;
constexpr size_t OFF_XB16 = OFF_OFGS + (size_t)cB * cNC1;       // cNB*cD u16 = /2 floats
constexpr size_t OFF_WB16 = OFF_XB16 + (size_t)cNB * cD / 2;    // cK*cD u16
constexpr size_t OFF_P    = OFF_WB16 + (size_t)cK * cD / 2;     // cNB int
constexpr size_t OFF_CNT  = OFF_P + cNB;                        // 1 u32

__device__ __forceinline__ u16 f2bf(float f) {
    unsigned u = __float_as_uint(f);
    u += 0x7fffu + ((u >> 16) & 1u);   // RNE
    return (u16)(u >> 16);
}
__device__ __forceinline__ u32 pk2(float a, float b) {
    return (u32)f2bf(a) | ((u32)f2bf(b) << 16);
}
// monotone float -> sortable uint (ascending)
__device__ __forceinline__ u32 f2sort(float f) {
    u32 b = __float_as_uint(f);
    u32 mask = (u32)((int)b >> 31);
    return b ^ (mask | 0x80000000u);
}
// software grid barrier, FIXED: spin on RELAXED agent-scope atomic load
// (coherent-point read, NO per-poll cache invalidation — R9's ACQUIRE-in-loop
// caused an invalidation storm, 120us idle). One full fence after exit
// provides the acquire. Release fence before arrive. s_sleep(8) ~512cyc/poll.
__device__ __forceinline__ void gbar(u32* cnt, u32 target) {
    __syncthreads();
    if (threadIdx.x == 0) {
        __threadfence();   // release: prior writes visible before arrive
        __hip_atomic_fetch_add(cnt, 1u, __ATOMIC_RELAXED, __HIP_MEMORY_SCOPE_AGENT);
        while (__hip_atomic_load(cnt, __ATOMIC_RELAXED, __HIP_MEMORY_SCOPE_AGENT) < target) {
            __builtin_amdgcn_s_sleep(8);
        }
        __threadfence();   // acquire: invalidate stale cached lines once
    }
    __syncthreads();
}

// ---------------------------------------------------------------------------
// k_prep (544 blocks): blocks <512: one pass over x -> xb16 (bf16) + exact
// f32 t1/t2 via in-block fold of Wa with Wb/Wc. Blocks >=512: Wa -> wab16.
// Block 512 also zero-inits the back-end barrier counter.
// ---------------------------------------------------------------------------
__global__ __launch_bounds__(256) void k_prep(
    const float* __restrict__ x, const float* __restrict__ Wa,
    const float* __restrict__ Wb, const float* __restrict__ wbb,
    const float* __restrict__ Wc, const float* __restrict__ wcb,
    u16* __restrict__ xb16, u16* __restrict__ wab16,
    float* __restrict__ t1, float* __restrict__ t2, u32* __restrict__ cnt)
{
    __shared__ float wabL[cD], wacL[cD];
    int t = threadIdx.x;
    if (blockIdx.x >= 512) {           // wprep slice: 32 blocks x 256 x 4 elems
        if (blockIdx.x == 512 && t == 0) cnt[0] = 0;
        int i4 = (((int)blockIdx.x - 512) * 256 + t) * 4;
        float4 v = *(const float4*)(Wa + i4);
        uint2 p = {pk2(v.x, v.y), pk2(v.z, v.w)};
        *(uint2*)(wab16 + i4) = p;
        return;
    }
    float s1a = 0.f, s2a = 0.f, s1b = 0.f, s2b = 0.f;
#pragma unroll 8
    for (int k = 0; k < cK; ++k) {
        float wbk = Wb[k], wck = Wc[k];
        float wa1 = Wa[k * cD + t];
        float wa2 = Wa[k * cD + t + 256];
        s1a += wa1 * wbk; s2a += wa1 * wck;
        s1b += wa2 * wbk; s2b += wa2 * wck;
    }
    wabL[t] = s1a; wacL[t] = s2a; wabL[t + 256] = s1b; wacL[t + 256] = s2b;
    __syncthreads();

    int w = t >> 6, lane = t & 63;
    int d1 = lane * 4, d2 = 256 + lane * 4;
    float4 wbA = *(const float4*)&wabL[d1], wbB = *(const float4*)&wabL[d2];
    float4 wcA = *(const float4*)&wacL[d1], wcB = *(const float4*)&wacL[d2];
    float wbbv = wbb[0], wcbv = wcb[0];
#pragma unroll 2
    for (int rr = 0; rr < 8; ++rr) {
        int row = blockIdx.x * 32 + w * 8 + rr;
        const float* xp = x + (size_t)row * cD;
        float4 a  = *(const float4*)(xp + d1);
        float4 bq = *(const float4*)(xp + d2);
        uint2 pa = {pk2(a.x, a.y), pk2(a.z, a.w)};
        uint2 pb = {pk2(bq.x, bq.y), pk2(bq.z, bq.w)};
        *(uint2*)(xb16 + (size_t)row * cD + d1) = pa;
        *(uint2*)(xb16 + (size_t)row * cD + d2) = pb;
        float p1 = a.x*wbA.x + a.y*wbA.y + a.z*wbA.z + a.w*wbA.w
                 + bq.x*wbB.x + bq.y*wbB.y + bq.z*wbB.z + bq.w*wbB.w;
        float p2 = a.x*wcA.x + a.y*wcA.y + a.z*wcA.z + a.w*wcA.w
                 + bq.x*wcB.x + bq.y*wcB.y + bq.z*wcB.z + bq.w*wcB.w;
#pragma unroll
        for (int off = 32; off > 0; off >>= 1) {
            p1 += __shfl_down(p1, off, 64);
            p2 += __shfl_down(p2, off, 64);
        }
        if (lane == 0) { t1[row] = p1 + wbbv; t2[row] = p2 + wcbv; }
    }
}

// ---------------------------------------------------------------------------
// k_projrank (768 blocks): <256 bf16-MFMA GEMM tiles; 256..511 brute-force
// rank (u64 keys in LDS); 512..767 p-search: p_i = #{j : t2_j < -T1_i}
// (float keys in LDS) == lower_bound(t2s, -T1_i). Slices co-schedule per CU.
// ---------------------------------------------------------------------------
__global__ __launch_bounds__(256) void k_projrank(
    const u16* __restrict__ xb16, const u16* __restrict__ wab16,
    const float* __restrict__ t2, const float* __restrict__ t1,
    float* __restrict__ h, float* __restrict__ t2s, int* __restrict__ idxs,
    int* __restrict__ pidx)
{
    __shared__ u64 shbuf[4096 + 128];   // 33.75 KB max (rank slice)
    int t = threadIdx.x;
    if (blockIdx.x < 256) {
        u16* xs = (u16*)shbuf;
        u16* was = xs + 64 * 32;
        int rowbase = blockIdx.x * 64;
        int w = t >> 6, lane = t & 63, m = lane & 15, quad = lane >> 4;
        int grow = w * 16 + (lane >> 2);
        int gcol = (lane & 3) * 8;
        const u16* xg = xb16 + (size_t)(rowbase + grow) * cD + gcol;
        const u16* wg = wab16 + (size_t)grow * cD + gcol;
        int lidx = grow * 32 + gcol;

        f32x4 acc[4] = {{0.f,0.f,0.f,0.f},{0.f,0.f,0.f,0.f},
                        {0.f,0.f,0.f,0.f},{0.f,0.f,0.f,0.f}};
        uint4 xv = *(const uint4*)(xg);
        uint4 wv = *(const uint4*)(wg);
        for (int s = 0; s < 16; ++s) {
            __syncthreads();
            *(uint4*)&xs[lidx] = xv;
            *(uint4*)&was[lidx] = wv;
            if (s < 15) {
                xv = *(const uint4*)(xg + (s + 1) * 32);
                wv = *(const uint4*)(wg + (s + 1) * 32);
            }
            __syncthreads();
            bf16x8 av = *(const bf16x8*)&xs[(w * 16 + m) * 32 + quad * 8];
#pragma unroll
            for (int g = 0; g < 4; ++g) {
                bf16x8 bv = *(const bf16x8*)&was[(g * 16 + m) * 32 + quad * 8];
                acc[g] = __builtin_amdgcn_mfma_f32_16x16x32_bf16(av, bv, acc[g], 0, 0, 0);
            }
        }
#pragma unroll
        for (int g = 0; g < 4; ++g) {
#pragma unroll
            for (int r4 = 0; r4 < 4; ++r4) {
                int row = w * 16 + quad * 4 + r4;
                h[(size_t)(rowbase + row) * cK + g * 16 + m] = acc[g][r4];
            }
        }
    } else if (blockIdx.x < 512) {
        u64* keys = shbuf;
        int* part = (int*)(shbuf + 4096);
        int rb = blockIdx.x - 256;
        int b = rb >> 6;
        int rowgrp = rb & 63;
        for (int i = t; i < cN; i += 256)
            keys[i] = ((u64)f2sort(t2[b * cN + i]) << 32) | (u32)i;
        __syncthreads();
        int lane = t & 63, subset = t >> 6;
        u64 mykey = keys[rowgrp * 64 + lane];
        int s0 = subset * 1024;
        int cnt = 0;
#pragma unroll 8
        for (int kk = 0; kk < 1024; ++kk)
            cnt += (keys[s0 + kk] < mykey) ? 1 : 0;
        part[subset * 64 + lane] = cnt;
        __syncthreads();
        if (t < 64) {
            int jj = rowgrp * 64 + t;
            int rank = part[t] + part[64 + t] + part[128 + t] + part[192 + t];
            t2s[b * cN + rank] = t2[b * cN + jj];
            idxs[b * cN + rank] = jj;
        }
    } else {
        float* keysf = (float*)shbuf;                 // 16 KB
        int* part = (int*)(shbuf + 2048);
        int rb = blockIdx.x - 512;
        int b = rb >> 6;
        int rowgrp = rb & 63;
        for (int i = t; i < cN; i += 256)
            keysf[i] = t2[b * cN + i];
        __syncthreads();
        int lane = t & 63, subset = t >> 6;
        float key = -t1[b * cN + rowgrp * 64 + lane];
        int s0 = subset * 1024;
        int cnt = 0;
#pragma unroll 8
        for (int kk = 0; kk < 1024; ++kk)
            cnt += (keysf[s0 + kk] < key) ? 1 : 0;
        part[subset * 64 + lane] = cnt;
        __syncthreads();
        if (t < 64) {
            pidx[b * cN + rowgrp * 64 + t] =
                part[t] + part[64 + t] + part[128 + t] + part[192 + t];
        }
    }
}

// ---------------------------------------------------------------------------
// k_backend (512 blocks x 256, launch_bounds(256,2) => all co-resident):
//  phase 1: 2048 wave-tasks = (batch, chunk-of-16, {E,G}) local scans
//  phase 2: 8 blocks do the two-level chunk-offset scans
//  phase 3: 8 rows/block output combine (p precomputed)
// separated by software grid barriers on cnt (monotonic targets 512, 1024).
// ---------------------------------------------------------------------------
__global__ __launch_bounds__(256, 2) void k_backend(
    const float* __restrict__ t1, const float* __restrict__ t2s,
    const int* __restrict__ idxs, const float* __restrict__ h,
    const int* __restrict__ pidx,
    float* __restrict__ EpL, float* __restrict__ GnL,
    float* __restrict__ eps_l, float* __restrict__ gns_l,
    float* __restrict__ chE, float* __restrict__ chG,
    float* __restrict__ chEs, float* __restrict__ chGs,
    float* __restrict__ ofE, float* __restrict__ ofG,
    float* __restrict__ ofEs, float* __restrict__ ofGs,
    const float* __restrict__ bias, float* __restrict__ out,
    u32* __restrict__ cnt)
{
    __shared__ float wsum[4][64];
    int t = threadIdx.x;
    int lane = t & 63, w = t >> 6;

    // ---- phase 1: chunk scans (one (b,c,dir) per wave) ----
    {
        int gw = blockIdx.x * 4 + w;       // 0..2047
        int dir = gw >> 10;                // 0 = E, 1 = G
        int b = (gw >> 8) & 3;
        int c = gw & 255;
        int base = b * cN + c * cCS;
        size_t rowbase = ((size_t)b * cNP + c * cCS) * cK;
        int sbase = b * cNP + c * cCS;
        float M2 = t2s[b * cN + cN - 1];
        int   idxv = (lane < cCS) ? idxs[base + lane] : 0;
        float t2v  = (lane < cCS) ? t2s[base + lane] : 0.f;
        float hv[cCS];
#pragma unroll
        for (int i = 0; i < cCS; ++i) {
            int j = __shfl(idxv, i, 64);
            hv[i] = h[((size_t)b * cN + j) * cK + lane];
        }
        if (dir == 0) {
            float ee[cCS];
#pragma unroll
            for (int i = 0; i < cCS; ++i)
                ee[i] = __expf(__shfl(t2v, i, 64) - M2);
            if (c == cNC - 1) {
                EpL[((size_t)b * cNP + cN) * cK + lane] = 0.f;
                if (lane == 0) eps_l[b * cNP + cN] = 0.f;
            }
            float acc = 0.f, accs = 0.f;
#pragma unroll
            for (int i = cCS - 1; i >= 0; --i) {
                acc += ee[i] * hv[i]; accs += ee[i];
                EpL[rowbase + (size_t)i * cK + lane] = acc;
                if (lane == 0) eps_l[sbase + i] = accs;
            }
            chE[((size_t)b * cNC + c) * cK + lane] = acc;
            if (lane == 0) chEs[b * cNC + c] = accs;
        } else {
            float gg[cCS];
#pragma unroll
            for (int i = 0; i < cCS; ++i)
                gg[i] = __expf(0.2f * (__shfl(t2v, i, 64) - M2));
            if (c == cNC - 1) {
                GnL[((size_t)b * cNP + cN) * cK + lane] = 0.f;
                if (lane == 0) gns_l[b * cNP + cN] = 0.f;
            }
            float acc = 0.f, accs = 0.f;
#pragma unroll
            for (int i = 0; i < cCS; ++i) {
                GnL[rowbase + (size_t)i * cK + lane] = acc;
                if (lane == 0) gns_l[sbase + i] = accs;
                acc += gg[i] * hv[i]; accs += gg[i];
            }
            chG[((size_t)b * cNC + c) * cK + lane] = acc;
            if (lane == 0) chGs[b * cNC + c] = accs;
        }
    }
    gbar(cnt, 512);

    // ---- phase 2: chunk-offset scans (blocks 0..7) ----
    if (blockIdx.x < 8) {
        int dir = blockIdx.x & 1;          // 0 = E(suffix), 1 = G(prefix)
        int b = blockIdx.x >> 1;
        const float* ch = dir ? chG : chE;
        float* of = dir ? ofG : ofE;
        int c0 = w * 64;
        float cv[64];
        float s = 0.f;
#pragma unroll
        for (int i = 0; i < 64; ++i) {
            cv[i] = ch[((size_t)b * cNC + c0 + i) * cK + lane];
            s += cv[i];
        }
        wsum[w][lane] = s;
        __syncthreads();
        float base = 0.f;
        if (dir == 0) { for (int w2 = w + 1; w2 < 4; ++w2) base += wsum[w2][lane]; }
        else          { for (int w2 = 0; w2 < w; ++w2) base += wsum[w2][lane]; }
        if (dir == 0) {
            float run = base;
#pragma unroll
            for (int i = 63; i >= 0; --i) {
                of[((size_t)b * cNC1 + c0 + i) * cK + lane] = run;
                run += cv[i];
            }
            if (w == 0) of[((size_t)b * cNC1 + cNC) * cK + lane] = 0.f;
        } else {
            float run = base;
#pragma unroll
            for (int i = 0; i < 64; ++i) {
                of[((size_t)b * cNC1 + c0 + i) * cK + lane] = run;
                run += cv[i];
            }
            if (w == 3) of[((size_t)b * cNC1 + cNC) * cK + lane] = run;
        }
        if (w == 0) {
            const float* chs = dir ? chGs : chEs;
            float* ofs = dir ? ofGs : ofEs;
            float e0 = chs[b * cNC + lane * 4 + 0];
            float e1 = chs[b * cNC + lane * 4 + 1];
            float e2 = chs[b * cNC + lane * 4 + 2];
            float e3 = chs[b * cNC + lane * 4 + 3];
            float p = e0 + e1 + e2 + e3;
            if (dir == 0) {
                float s2 = p;
#pragma unroll
                for (int off = 1; off < 64; off <<= 1) {
                    float tv = __shfl_down(s2, off, 64);
                    if (lane + off < 64) s2 += tv;
                }
                float excl = s2 - p;
                ofs[b * cNC1 + lane * 4 + 0] = excl + e1 + e2 + e3;
                ofs[b * cNC1 + lane * 4 + 1] = excl + e2 + e3;
                ofs[b * cNC1 + lane * 4 + 2] = excl + e3;
                ofs[b * cNC1 + lane * 4 + 3] = excl;
                if (lane == 0) ofs[b * cNC1 + cNC] = 0.f;
            } else {
                float s2 = p;
#pragma unroll
                for (int off = 1; off < 64; off <<= 1) {
                    float tv = __shfl_up(s2, off, 64);
                    if (lane >= off) s2 += tv;
                }
                float excl = s2 - p;
                ofs[b * cNC1 + lane * 4 + 0] = excl;
                ofs[b * cNC1 + lane * 4 + 1] = excl + e0;
                ofs[b * cNC1 + lane * 4 + 2] = excl + e0 + e1;
                ofs[b * cNC1 + lane * 4 + 3] = excl + e0 + e1 + e2;
                if (lane == 63) ofs[b * cNC1 + cNC] = s2;
            }
        }
    }
    gbar(cnt, 1024);

    // ---- phase 3: output combine, 8 rows/block ----
#pragma unroll 2
    for (int g = 0; g < 8; ++g) {
        int r = g * 2048 + blockIdx.x * 4 + w;
        int b = r >> 12;
        float T1 = t1[r];
        float M2 = t2s[b * cN + cN - 1];
        float smax = T1 + M2;
        float m = fmaxf(smax, 0.2f * smax);
        float A  = __expf(smax - m);
        float Cc = __expf(0.2f * smax - m);
        int p = pidx[r];
        int c = p >> 4;
        size_t pr = ((size_t)b * cNP + p) * cK + lane;
        size_t cr = ((size_t)b * cNC1 + c) * cK + lane;
        float num = A * (EpL[pr] + ofE[cr]) + Cc * (GnL[pr] + ofG[cr]);
        float den = A * (eps_l[(size_t)b * cNP + p] + ofEs[b * cNC1 + c])
                  + Cc * (gns_l[(size_t)b * cNP + p] + ofGs[b * cNC1 + c]);
        out[(size_t)r * cK + lane] = num / den + bias[lane];
    }
}

// ---------------------------------------------------------------------------
extern "C" void kernel_launch(void* const* d_in, const int* in_sizes, int n_in,
                              void* d_out, int out_size, void* d_ws, size_t ws_size,
                              hipStream_t stream)
{
    const float* x    = (const float*)d_in[0];
    const float* Wa   = (const float*)d_in[1];
    const float* Wb   = (const float*)d_in[2];
    const float* wbb  = (const float*)d_in[3];
    const float* Wc   = (const float*)d_in[4];
    const float* wcb  = (const float*)d_in[5];
    const float* bias = (const float*)d_in[6];
    float* out = (float*)d_out;

    float* ws = (float*)d_ws;
    float* h     = ws + OFF_H;
    float* t1    = ws + OFF_T1;
    float* t2    = ws + OFF_T2;
    float* t2s   = ws + OFF_T2S;
    int*   idxs  = (int*)(ws + OFF_IDX);
    float* EpL   = ws + OFF_EPL;
    float* GnL   = ws + OFF_GNL;
    float* eps_l = ws + OFF_EPS;
    float* gns_l = ws + OFF_GNS;
    float* chE   = ws + OFF_CHE;
    float* chG   = ws + OFF_CHG;
    float* chEs  = ws + OFF_CHES;
    float* chGs  = ws + OFF_CHGS;
    float* ofE   = ws + OFF_OFE;
    float* ofG   = ws + OFF_OFG;
    float* ofEs  = ws + OFF_OFES;
    float* ofGs  = ws + OFF_OFGS;
    u16*   xb16  = (u16*)(ws + OFF_XB16);
    u16*   wab16 = (u16*)(ws + OFF_WB16);
    int*   pidx  = (int*)(ws + OFF_P);
    u32*   cnt   = (u32*)(ws + OFF_CNT);

    k_prep<<<544, 256, 0, stream>>>(x, Wa, Wb, wbb, Wc, wcb, xb16, wab16, t1, t2, cnt);
    k_projrank<<<768, 256, 0, stream>>>(xb16, wab16, t2, t1, h, t2s, idxs, pidx);
    k_backend<<<512, 256, 0, stream>>>(t1, t2s, idxs, h, pidx,
                                       EpL, GnL, eps_l, gns_l,
                                       chE, chG, chEs, chGs,
                                       ofE, ofG, ofEs, ofGs,
                                       bias, out, cnt);
}